// Round 13
// baseline (449.800 us; speedup 1.0000x reference)
//
#include <hip/hip_runtime.h>

#define GG 256

typedef __bf16 bf16x8 __attribute__((ext_vector_type(8)));
typedef __bf16 bf16x4 __attribute__((ext_vector_type(4)));
typedef float floatx4 __attribute__((ext_vector_type(4)));
typedef float f32x2 __attribute__((ext_vector_type(2)));

__device__ __forceinline__ float lrelu(float x) { return x > 0.f ? x : 0.2f * x; }

// column permutation within each 64-col group: compute-order -> consecutive true cols
__device__ __forceinline__ int permM(int m) {
    int g = m >> 6, q = m & 63;
    return (g << 6) | ((q & 3) << 4) | (q >> 2);
}

// ---- fused weight prep (B rows stored permuted; attn mini-tile unpermuted) ----
__device__ __forceinline__ void wt1(const float* __restrict__ B, __bf16* __restrict__ Bt,
                                    int K, int M, int idx) {
    int k = idx / M, m = idx - k * M;
    Bt[(size_t)permM(m) * K + k] = (__bf16)B[idx];
}
__device__ __forceinline__ void wattn1(const float* __restrict__ W,
                                       const float* __restrict__ as_,
                                       const float* __restrict__ ad_,
                                       __bf16* __restrict__ dst, int K, int C, int idx) {
    int j = idx / K, k = idx - j * K;
    float v = 0.f;
    if (j < 8) {
        int h = j & 3;
        const float* att = (j < 4) ? as_ : ad_;
        int M = 4 * C;
        for (int c = 0; c < C; c++) v += W[(size_t)k * M + h * C + c] * att[h * C + c];
    }
    dst[(size_t)j * K + k] = (__bf16)v;
}

__global__ void k_wprep(const float* W1, const float* lw1, const float* as1, const float* ad1,
                        const float* W2, const float* lw2, const float* as2, const float* ad2,
                        const float* W3, const float* lw3, const float* as3, const float* ad3,
                        __bf16* B1t, __bf16* B2t, __bf16* B3t) {
    int idx = blockIdx.x * blockDim.x + threadIdx.x;
    if (idx < 32768) { wt1(W1, B1t, 128, 256, idx); return; }
    idx -= 32768;
    if (idx < 32768) { wt1(lw1, B1t + 256 * 128, 128, 256, idx); return; }
    idx -= 32768;
    if (idx < 2048) { wattn1(W1, as1, ad1, B1t + 512 * 128, 128, 64, idx); return; }
    idx -= 2048;
    if (idx < 65536) { wt1(W2, B2t, 256, 256, idx); return; }
    idx -= 65536;
    if (idx < 65536) { wt1(lw2, B2t + 256 * 256, 256, 256, idx); return; }
    idx -= 65536;
    if (idx < 4096) { wattn1(W2, as2, ad2, B2t + 512 * 256, 256, 64, idx); return; }
    idx -= 4096;
    if (idx < 131072) { wt1(W3, B3t, 256, 512, idx); return; }
    idx -= 131072;
    if (idx < 32768) { wt1(lw3, B3t + 512 * 256, 256, 128, idx); return; }
    idx -= 32768;
    if (idx < 4096) { wattn1(W3, as3, ad3, B3t + 640 * 256, 256, 128, idx); }
}

// All-in-one GEMM (64-row blocks, register-pipelined B staging, packed epilogue).
template <int K, bool EMB, bool LINBF>
__global__ __launch_bounds__(256) void k_gemm_all(const __bf16* __restrict__ A,
                                                  const int* __restrict__ xl,
                                                  const int* __restrict__ xr,
                                                  const float* __restrict__ emb,
                                                  const __bf16* __restrict__ Bt,
                                                  int n, int n1, int Mx, int Ml,
                                                  unsigned char* __restrict__ x8, int ldx,
                                                  float* __restrict__ linf,
                                                  __bf16* __restrict__ linb, int ldl,
                                                  const float* __restrict__ bias1,
                                                  const float* __restrict__ bias2,
                                                  float* __restrict__ a_s,
                                                  float* __restrict__ a_d) {
    constexpr int KS = K / 32;
    constexpr int LDK = K + 8;
    constexpr int LPR = K / 8;
    constexpr int NCH = 64 * LPR / 256;
    __shared__ __bf16 S[64 * LDK];
    int tid = threadIdx.x;
    int wave = tid >> 6, lane = tid & 63;
    int row0 = blockIdx.x * 64;
#pragma unroll
    for (int c = 0; c < NCH; c++) {
        int i = tid + c * 256;
        int r = i / LPR, ko = (i - r * LPR) * 8;
        int gr = row0 + r;
        bf16x8 v = {};
        if (gr < n) {
            if (EMB) {
                int xi = (gr < n1) ? xl[gr] : xr[gr - n1];
                const float4* src = (const float4*)(emb + ((size_t)xi << 7) + ko);
                float4 q0 = src[0], q1 = src[1];
                v = bf16x8{(__bf16)q0.x, (__bf16)q0.y, (__bf16)q0.z, (__bf16)q0.w,
                           (__bf16)q1.x, (__bf16)q1.y, (__bf16)q1.z, (__bf16)q1.w};
            } else {
                v = *(const bf16x8*)(A + (size_t)gr * K + ko);
            }
        }
        *(bf16x8*)&S[r * LDK + ko] = v;
    }
    __syncthreads();
    int kOff = (lane >> 4) * 8;
    int colBase = lane & 15;
    bf16x8 af[KS];
#pragma unroll
    for (int ks = 0; ks < KS; ks++)
        af[ks] = *(const bf16x8*)&S[(wave * 16 + colBase) * LDK + ks * 32 + kOff];
    int Mtot = Mx + Ml;
    int gr0 = row0 + wave * 16 + ((lane >> 4) << 2);
    int half = (Mtot / 128) * 64;
    int c0beg = blockIdx.y * half;
    int T = half / 64;
    bf16x8 regs[NCH];
#pragma unroll
    for (int c = 0; c < NCH; c++) {
        int i = tid + c * 256;
        int r = i / LPR, ko = (i - r * LPR) * 8;
        regs[c] = *(const bf16x8*)(Bt + (size_t)(c0beg + r) * K + ko);
    }
    for (int t = 0; t < T; t++) {
        __syncthreads();
#pragma unroll
        for (int c = 0; c < NCH; c++) {
            int i = tid + c * 256;
            int r = i / LPR, ko = (i - r * LPR) * 8;
            *(bf16x8*)&S[r * LDK + ko] = regs[c];
        }
        if (t + 1 < T) {
            int c0n = c0beg + (t + 1) * 64;
#pragma unroll
            for (int c = 0; c < NCH; c++) {
                int i = tid + c * 256;
                int r = i / LPR, ko = (i - r * LPR) * 8;
                regs[c] = *(const bf16x8*)(Bt + (size_t)(c0n + r) * K + ko);
            }
        }
        __syncthreads();
        floatx4 acc[4] = {};
#pragma unroll
        for (int ct = 0; ct < 4; ct++) {
#pragma unroll
            for (int ks = 0; ks < KS; ks++) {
                bf16x8 bf = *(const bf16x8*)&S[(ct * 16 + colBase) * LDK + ks * 32 + kOff];
                acc[ct] = __builtin_amdgcn_mfma_f32_16x16x32_bf16(af[ks], bf, acc[ct], 0, 0, 0);
            }
        }
        int c0 = c0beg + t * 64;
        if (c0 < Mx) {  // packed fp8 dword store per row
#pragma unroll
            for (int r = 0; r < 4; r++) {
                int gr = gr0 + r;
                if (gr >= n) continue;
                int p = __builtin_amdgcn_cvt_pk_fp8_f32(acc[0][r], acc[1][r], 0, false);
                p = __builtin_amdgcn_cvt_pk_fp8_f32(acc[2][r], acc[3][r], p, true);
                *(unsigned int*)(x8 + (size_t)gr * ldx + c0 + colBase * 4) = (unsigned int)p;
            }
        } else {
            int c2 = c0 + colBase * 4 - Mx;
#pragma unroll
            for (int r = 0; r < 4; r++) {
                int gr = gr0 + r;
                if (gr >= n) continue;
                float v0 = acc[0][r] + bias1[c2 + 0];
                float v1 = acc[1][r] + bias1[c2 + 1];
                float v2 = acc[2][r] + bias1[c2 + 2];
                float v3 = acc[3][r] + bias1[c2 + 3];
                if (bias2) {
                    v0 += bias2[c2 + 0]; v1 += bias2[c2 + 1];
                    v2 += bias2[c2 + 2]; v3 += bias2[c2 + 3];
                }
                if (LINBF) {
                    bf16x4 o = {(__bf16)v0, (__bf16)v1, (__bf16)v2, (__bf16)v3};
                    *(bf16x4*)(linb + (size_t)gr * ldl + c2) = o;
                } else {
                    float4 o = {v0, v1, v2, v3};
                    *(float4*)(linf + (size_t)gr * ldl + c2) = o;
                }
            }
        }
    }
    if (blockIdx.y == 1) {  // attn mini-tile (unpermuted rows)
        floatx4 acc = {};
        const __bf16* bp = Bt + (size_t)(Mtot + colBase) * K + kOff;
#pragma unroll
        for (int ks = 0; ks < KS; ks++) {
            bf16x8 bf = *(const bf16x8*)(bp + ks * 32);
            acc = __builtin_amdgcn_mfma_f32_16x16x32_bf16(af[ks], bf, acc, 0, 0, 0);
        }
        if (colBase < 8) {
            float* dst = (colBase < 4) ? a_s : a_d;
            int h = colBase & 3;
#pragma unroll
            for (int r = 0; r < 4; r++) {
                int gr = gr0 + r;
                if (gr < n) dst[gr * 4 + h] = acc[r];
            }
        }
    }
}

// ---- combined-CSR build (side-1 ids offset by n) ----
__global__ void k_hist2(const int* __restrict__ el, const int* __restrict__ er,
                        int E, int n, int* __restrict__ deg) {
    int e = blockIdx.x * blockDim.x + threadIdx.x;
    if (e >= 2 * E) return;
    int d = (e < E) ? el[E + e] : er[E + (e - E)] + n;
    atomicAdd(&deg[d], 1);
}

// ---- 3-pass parallel exclusive scan over rp[0..n) ----
__global__ __launch_bounds__(1024) void k_scan1(int* __restrict__ rp, int n,
                                                int* __restrict__ part) {
    __shared__ int wsum[16];
    int i = blockIdx.x * 1024 + threadIdx.x;
    int lane = threadIdx.x & 63, wid = threadIdx.x >> 6;
    int v = (i < n) ? rp[i] : 0;
    int inc = v;
#pragma unroll
    for (int off = 1; off < 64; off <<= 1) {
        int t = __shfl_up(inc, off, 64);
        if (lane >= off) inc += t;
    }
    if (lane == 63) wsum[wid] = inc;
    __syncthreads();
    if (wid == 0) {
        int wv = (lane < 16) ? wsum[lane] : 0;
        int winc = wv;
#pragma unroll
        for (int off = 1; off < 16; off <<= 1) {
            int t = __shfl_up(winc, off, 64);
            if (lane >= off) winc += t;
        }
        if (lane < 16) wsum[lane] = winc - wv;  // exclusive wave offsets
        if (lane == 15) part[blockIdx.x] = winc;  // block total
    }
    __syncthreads();
    if (i < n) rp[i] = wsum[wid] + (inc - v);  // block-local exclusive
}

__global__ void k_scan2(int* __restrict__ part, int nb) {
    int lane = threadIdx.x;
    int v = (lane < nb) ? part[lane] : 0;
    int inc = v;
#pragma unroll
    for (int off = 1; off < 64; off <<= 1) {
        int t = __shfl_up(inc, off, 64);
        if (lane >= off) inc += t;
    }
    if (lane < nb) part[lane] = inc - v;  // exclusive
}

__global__ __launch_bounds__(1024) void k_scan3(int* __restrict__ rp, int n,
                                                const int* __restrict__ part) {
    int i = blockIdx.x * 1024 + threadIdx.x;
    if (i < n) rp[i] += part[blockIdx.x];
}

__global__ void k_fill2(const int* __restrict__ el, const int* __restrict__ er,
                        int E, int n, int* __restrict__ rp, int* __restrict__ csr) {
    int e = blockIdx.x * blockDim.x + threadIdx.x;
    if (e >= 2 * E) return;
    int d, s;
    if (e < E) { s = el[e]; d = el[E + e]; }
    else       { s = er[e - E] + n; d = er[E + (e - E)] + n; }
    int pos = atomicAdd(&rp[d], 1);
    csr[pos] = s;
}

template <bool HI>
__device__ __forceinline__ f32x2 cvt2(unsigned int u) {
    return __builtin_amdgcn_cvt_pk_f32_fp8(u, HI);
}

// side-split XCD swizzle: blocks with bid%8 in {0..3} take side-L node blocks,
// {4..7} take side-R -> each XCD's gather footprint is one side's table only.
__device__ __forceinline__ int swz_block(int bid, int nbx) {
    if (nbx & 7) return bid;           // safety: needs nbx % 8 == 0
    int halfb = nbx >> 1;
    int grp = bid >> 3, r = bid & 7;
    int j = grp * 4 + (r & 3);
    return (r < 4) ? j : halfb + j;
}

// Layers 1/2 aggregation on fp8 rows (256 B): ONE node per wave, FOUR
// quarter-wave edge streams (16 lanes x 16 B each) -> 4 edges/iteration,
// loop length ceil(d/4). Rotating depth-3 prefetch (unroll-3 renames the
// rotation away); clamped in-loop prefetch. f32x2 packed accumulation
// (v_pk_fma_f32). Cross-quarter merge via shfl_xor(16)+shfl_xor(32).
__global__ __launch_bounds__(256) void k_agg12(const int* __restrict__ rp,
                                               const int* __restrict__ csr,
                                               const float* __restrict__ a_s,
                                               const float* __restrict__ a_d,
                                               const unsigned char* __restrict__ x8,
                                               const __bf16* __restrict__ lin,
                                               __bf16* __restrict__ out_bf, int n) {
    int nb = swz_block(blockIdx.x, gridDim.x);
    int lane = threadIdx.x & 63;
    int q = lane >> 4, sl = lane & 15;
    int node = nb * 4 + (threadIdx.x >> 6);
    if (node >= n) return;
    int c0 = sl * 16;   // byte/value column in 256-wide row
    int h = sl >> 2;
    int start = node ? rp[node - 1] : 0;
    int end = rp[node];
    float ad = a_d[node * 4 + h];
    float z = 0.f;
    f32x2 acc[8] = {};  // value j lives at acc[j>>1][j&1]
    if (q == 0) {  // self-loop term once
        z = __expf(lrelu(a_s[node * 4 + h] + ad));
        uint4 u = *(const uint4*)(x8 + (size_t)node * 256 + c0);
        f32x2 zz = {z, z};
        acc[0] = zz * cvt2<false>(u.x); acc[1] = zz * cvt2<true>(u.x);
        acc[2] = zz * cvt2<false>(u.y); acc[3] = zz * cvt2<true>(u.y);
        acc[4] = zz * cvt2<false>(u.z); acc[5] = zz * cvt2<true>(u.z);
        acc[6] = zz * cvt2<false>(u.w); acc[7] = zz * cvt2<true>(u.w);
    }
    uint4 u0 = {}, u1 = {}, u2 = {};
    float A0 = 0.f, A1 = 0.f, A2 = 0.f;
    int e0 = start + q;
    if (e0 < end) {
        int s = csr[e0];
        u0 = *(const uint4*)(x8 + (size_t)s * 256 + c0);
        A0 = a_s[s * 4 + h];
    }
    if (e0 + 4 < end) {
        int s = csr[e0 + 4];
        u1 = *(const uint4*)(x8 + (size_t)s * 256 + c0);
        A1 = a_s[s * 4 + h];
    }
    if (e0 + 8 < end) {
        int s = csr[e0 + 8];
        u2 = *(const uint4*)(x8 + (size_t)s * 256 + c0);
        A2 = a_s[s * 4 + h];
    }
#pragma unroll 3
    for (int e = e0; e < end; e += 4) {
        uint4 uc = u0;
        float ac = A0;
        u0 = u1; A0 = A1;
        u1 = u2; A1 = A2;
        int pn = e + 12;
        pn = pn < end ? pn : end - 1;  // loop entered => end >= 1
        int s = csr[pn];
        u2 = *(const uint4*)(x8 + (size_t)s * 256 + c0);
        A2 = a_s[s * 4 + h];
        float w = __expf(lrelu(ac + ad));
        z += w;
        f32x2 wv = {w, w};
        acc[0] += wv * cvt2<false>(uc.x); acc[1] += wv * cvt2<true>(uc.x);
        acc[2] += wv * cvt2<false>(uc.y); acc[3] += wv * cvt2<true>(uc.y);
        acc[4] += wv * cvt2<false>(uc.z); acc[5] += wv * cvt2<true>(uc.z);
        acc[6] += wv * cvt2<false>(uc.w); acc[7] += wv * cvt2<true>(uc.w);
    }
    z += __shfl_xor(z, 16, 64);
    z += __shfl_xor(z, 32, 64);
#pragma unroll
    for (int k = 0; k < 8; k++) {
#pragma unroll
        for (int e2 = 0; e2 < 2; e2++) {
            float v = acc[k][e2];
            v += __shfl_xor(v, 16, 64);
            v += __shfl_xor(v, 32, 64);
            acc[k][e2] = v;
        }
    }
    if (q == 0) {
        float inv = 1.f / (z + 1e-16f);
        const __bf16* lp = lin + (size_t)node * 256 + c0;
        bf16x8 l0 = *(const bf16x8*)lp;
        bf16x8 l1 = *(const bf16x8*)(lp + 8);
        bf16x8 r0, r1;
#pragma unroll
        for (int j = 0; j < 8; j++) {
            r0[j] = (__bf16)fmaxf(acc[j >> 1][j & 1] * inv + (float)l0[j], 0.f);
            r1[j] = (__bf16)fmaxf(acc[4 + (j >> 1)][j & 1] * inv + (float)l1[j], 0.f);
        }
        __bf16* op = out_bf + (size_t)node * 256 + c0;
        *(bf16x8*)op = r0;
        *(bf16x8*)(op + 8) = r1;
    }
}

// Layer-3 aggregation (HC=512): ONE node per wave, FOUR quarter-wave edge
// streams (16 lanes x 32 B each = two uint4 loads/lane) -> 4 edges/iteration,
// loop length ceil(d/4). Rotating depth-2 prefetch per stream (4 outstanding
// loads/lane), clamped in-loop index, f32x2 packed accumulation.
// Lane (q,sl) holds dwords sl*8..sl*8+7 (head sl>>2, cols (sl&3)*32..+31).
// Merge: xor16/32 (streams) -> scale 0.25/z -> xor4/8 (heads) ->
// lanes 0-3 store 32 mean cols each.
__global__ __launch_bounds__(256) void k_agg3(const int* __restrict__ rp,
                                              const int* __restrict__ csr,
                                              const float* __restrict__ a_s,
                                              const float* __restrict__ a_d,
                                              const unsigned int* __restrict__ x8,
                                              float* __restrict__ mean, int n) {
    int nb = swz_block(blockIdx.x, gridDim.x);
    int lane = threadIdx.x & 63;
    int q = lane >> 4, sl = lane & 15;
    int node = nb * 4 + (threadIdx.x >> 6);
    if (node >= n) return;
    int dwb = sl * 8;      // dword offset of this lane's 32-value chunk
    int h = sl >> 2;       // head of the chunk
    int start = node ? rp[node - 1] : 0;
    int end = rp[node];
    float ad = a_d[node * 4 + h];
    float z = 0.f;
    f32x2 acc[16] = {};  // value j (0..31) lives at acc[j>>1][j&1]
    if (q == 0) {  // self-loop term once
        z = __expf(lrelu(a_s[node * 4 + h] + ad));
        const uint4* sp = (const uint4*)(x8 + (size_t)node * 128 + dwb);
        uint4 ua = sp[0], ub = sp[1];
        f32x2 zz = {z, z};
        acc[0] = zz * cvt2<false>(ua.x);  acc[1] = zz * cvt2<true>(ua.x);
        acc[2] = zz * cvt2<false>(ua.y);  acc[3] = zz * cvt2<true>(ua.y);
        acc[4] = zz * cvt2<false>(ua.z);  acc[5] = zz * cvt2<true>(ua.z);
        acc[6] = zz * cvt2<false>(ua.w);  acc[7] = zz * cvt2<true>(ua.w);
        acc[8] = zz * cvt2<false>(ub.x);  acc[9] = zz * cvt2<true>(ub.x);
        acc[10] = zz * cvt2<false>(ub.y); acc[11] = zz * cvt2<true>(ub.y);
        acc[12] = zz * cvt2<false>(ub.z); acc[13] = zz * cvt2<true>(ub.z);
        acc[14] = zz * cvt2<false>(ub.w); acc[15] = zz * cvt2<true>(ub.w);
    }
    uint4 u0a = {}, u0b = {}, u1a = {}, u1b = {};
    float A0 = 0.f, A1 = 0.f;
    int e0 = start + q;
    if (e0 < end) {
        int s = csr[e0];
        const uint4* sp = (const uint4*)(x8 + (size_t)s * 128 + dwb);
        u0a = sp[0]; u0b = sp[1];
        A0 = a_s[s * 4 + h];
    }
    if (e0 + 4 < end) {
        int s = csr[e0 + 4];
        const uint4* sp = (const uint4*)(x8 + (size_t)s * 128 + dwb);
        u1a = sp[0]; u1b = sp[1];
        A1 = a_s[s * 4 + h];
    }
#pragma unroll 2
    for (int e = e0; e < end; e += 4) {
        uint4 uca = u0a, ucb = u0b;
        float ac = A0;
        u0a = u1a; u0b = u1b; A0 = A1;
        int pn = e + 8;
        pn = pn < end ? pn : end - 1;  // loop entered => end >= 1
        int s = csr[pn];
        const uint4* sp = (const uint4*)(x8 + (size_t)s * 128 + dwb);
        u1a = sp[0]; u1b = sp[1];
        A1 = a_s[s * 4 + h];
        float w = __expf(lrelu(ac + ad));
        z += w;
        f32x2 wv = {w, w};
        acc[0] += wv * cvt2<false>(uca.x);  acc[1] += wv * cvt2<true>(uca.x);
        acc[2] += wv * cvt2<false>(uca.y);  acc[3] += wv * cvt2<true>(uca.y);
        acc[4] += wv * cvt2<false>(uca.z);  acc[5] += wv * cvt2<true>(uca.z);
        acc[6] += wv * cvt2<false>(uca.w);  acc[7] += wv * cvt2<true>(uca.w);
        acc[8] += wv * cvt2<false>(ucb.x);  acc[9] += wv * cvt2<true>(ucb.x);
        acc[10] += wv * cvt2<false>(ucb.y); acc[11] += wv * cvt2<true>(ucb.y);
        acc[12] += wv * cvt2<false>(ucb.z); acc[13] += wv * cvt2<true>(ucb.z);
        acc[14] += wv * cvt2<false>(ucb.w); acc[15] += wv * cvt2<true>(ucb.w);
    }
    z += __shfl_xor(z, 16, 64);   // merge streams -> full denominator
    z += __shfl_xor(z, 32, 64);
    float sc = 0.25f / (z + 1e-16f);
#pragma unroll
    for (int k = 0; k < 16; k++) {
#pragma unroll
        for (int e2 = 0; e2 < 2; e2++) {
            float v = acc[k][e2];
            v += __shfl_xor(v, 16, 64);   // merge streams
            v += __shfl_xor(v, 32, 64);
            v *= sc;                      // per-head scale
            v += __shfl_xor(v, 4, 64);    // merge heads (sl bit 2)
            v += __shfl_xor(v, 8, 64);    // merge heads (sl bit 3)
            acc[k][e2] = v;
        }
    }
    if (lane < 4) {  // lane holds mean cols 32*lane .. 32*lane+31
        float4* op = (float4*)(mean + (size_t)node * 128 + lane * 32);
#pragma unroll
        for (int k = 0; k < 8; k++) {
            float4 o = {acc[2 * k][0], acc[2 * k][1], acc[2 * k + 1][0], acc[2 * k + 1][1]};
            op[k] = o;
        }
    }
}

// per-graph mean pool (2G blocks), inline binary search on sorted batch
__global__ __launch_bounds__(128) void k_pool(const float* __restrict__ mean,
                                              const float* __restrict__ lin3,
                                              const float* __restrict__ b3,
                                              const int* __restrict__ bl,
                                              const int* __restrict__ br,
                                              int n, float* __restrict__ out) {
    int g = blockIdx.x, c = threadIdx.x;
    const int* b = (g < GG) ? bl : br;
    int tg = (g < GG) ? g : g - GG;
    int off = (g < GG) ? 0 : n;
    int s, e;
    { int lo = 0, hi = n; while (lo < hi) { int m = (lo + hi) >> 1; if (b[m] < tg) lo = m + 1; else hi = m; } s = lo; }
    { int lo = 0, hi = n; while (lo < hi) { int m = (lo + hi) >> 1; if (b[m] < tg + 1) lo = m + 1; else hi = m; } e = lo; }
    s += off; e += off;
    float acc = 0.f;
    for (int i = s; i < e; i++)
        acc += mean[(size_t)i * 128 + c] + lin3[(size_t)i * 128 + c];
    int cnt = e - s;
    out[(size_t)g * 128 + c] = cnt > 0 ? acc / (float)cnt + b3[c] : 0.f;
}

static inline int cdiv(int a, int b) { return (a + b - 1) / b; }

extern "C" void kernel_launch(void* const* d_in, const int* in_sizes, int n_in,
                              void* d_out, int out_size, void* d_ws, size_t ws_size,
                              hipStream_t stream) {
    const int* x_l = (const int*)d_in[0];
    const int* edge_l = (const int*)d_in[1];
    const int* batch_l = (const int*)d_in[2];
    const int* x_r = (const int*)d_in[3];
    const int* edge_r = (const int*)d_in[4];
    const int* batch_r = (const int*)d_in[5];
    const float* emb = (const float*)d_in[6];
    const float* W1 = (const float*)d_in[7];
    const float* as1 = (const float*)d_in[8];
    const float* ad1 = (const float*)d_in[9];
    const float* b1 = (const float*)d_in[10];
    const float* lw1 = (const float*)d_in[11];
    const float* lb1 = (const float*)d_in[12];
    const float* W2 = (const float*)d_in[13];
    const float* as2 = (const float*)d_in[14];
    const float* ad2 = (const float*)d_in[15];
    const float* b2 = (const float*)d_in[16];
    const float* lw2 = (const float*)d_in[17];
    const float* lb2 = (const float*)d_in[18];
    const float* W3 = (const float*)d_in[19];
    const float* as3 = (const float*)d_in[20];
    const float* ad3 = (const float*)d_in[21];
    const float* b3 = (const float*)d_in[22];
    const float* lw3 = (const float*)d_in[23];
    const float* lb3 = (const float*)d_in[24];

    const int n = in_sizes[0];       // 20000
    const int E = in_sizes[1] / 2;   // 320000
    const int N2 = 2 * n;
    const int NB = cdiv(N2, 1024);   // scan blocks (40 <= 64)

    float* MEAN = (float*)d_ws;                // [N2,128]
    float* L3 = MEAN + (size_t)N2 * 128;       // [N2,128] fp32 layer-3 skip
    float* a_s = L3 + (size_t)N2 * 128;        // [N2,4]
    float* a_d = a_s + (size_t)N2 * 4;
    int* rp = (int*)(a_d + (size_t)N2 * 4);    // [N2]
    int* csr = rp + N2;                        // [2E]
    int* part = csr + 2 * E;                   // [64] scan partials
    __bf16* LINb = (__bf16*)(part + 64);       // [N2,256] bf16 skip (layers 1/2)
    unsigned char* X8a = (unsigned char*)(LINb + (size_t)N2 * 256);  // [N2,256] fp8
    unsigned char* X8b = X8a + (size_t)N2 * 256;                     // [N2,512] fp8
    __bf16* Abf = (__bf16*)(X8b + (size_t)N2 * 512);                 // [N2,256] GEMM A
    __bf16* B1t = Abf + (size_t)N2 * 256;  // 528 x 128
    __bf16* B2t = B1t + 528 * 128;         // 528 x 256
    __bf16* B3t = B2t + 528 * 256;         // 656 x 256

    const int TB = 256;
    dim3 blk(TB);

    // fused weight prep (1 dispatch)
    k_wprep<<<cdiv(370688, TB), blk, 0, stream>>>(W1, lw1, as1, ad1, W2, lw2, as2, ad2,
                                                  W3, lw3, as3, ad3, B1t, B2t, B3t);

    // combined CSR (once for all 3 layers, both sides), parallel scan
    hipMemsetAsync(rp, 0, sizeof(int) * (size_t)N2, stream);
    k_hist2<<<cdiv(2 * E, TB), blk, 0, stream>>>(edge_l, edge_r, E, n, rp);
    k_scan1<<<NB, 1024, 0, stream>>>(rp, N2, part);
    k_scan2<<<1, 64, 0, stream>>>(part, NB);
    k_scan3<<<NB, 1024, 0, stream>>>(rp, N2, part);
    k_fill2<<<cdiv(2 * E, TB), blk, 0, stream>>>(edge_l, edge_r, E, n, rp, csr);

    // ---- layer 1 (K=128, embed fused, Mx=256 -> fp8, Ml=256 -> bf16 lin) ----
    k_gemm_all<128, true, true><<<dim3(cdiv(N2, 64), 2), blk, 0, stream>>>(
        nullptr, x_l, x_r, emb, B1t, N2, n, 256, 256, X8a, 256, nullptr, LINb, 256, lb1, b1, a_s, a_d);
    k_agg12<<<cdiv(N2, 4), blk, 0, stream>>>(rp, csr, a_s, a_d, X8a, LINb, Abf, N2);

    // ---- layer 2 (K=256, Mx=256 -> fp8, Ml=256 -> bf16 lin) ----
    k_gemm_all<256, false, true><<<dim3(cdiv(N2, 64), 2), blk, 0, stream>>>(
        Abf, nullptr, nullptr, nullptr, B2t, N2, n, 256, 256, X8a, 256, nullptr, LINb, 256, lb2, b2, a_s, a_d);
    k_agg12<<<cdiv(N2, 4), blk, 0, stream>>>(rp, csr, a_s, a_d, X8a, LINb, Abf, N2);

    // ---- layer 3 (K=256, Mx=512 -> fp8, Ml=128 -> fp32 L3) ----
    k_gemm_all<256, false, false><<<dim3(cdiv(N2, 64), 2), blk, 0, stream>>>(
        Abf, nullptr, nullptr, nullptr, B3t, N2, n, 512, 128, X8b, 512, L3, nullptr, 128, lb3, nullptr, a_s, a_d);
    k_agg3<<<cdiv(N2, 4), blk, 0, stream>>>(rp, csr, a_s, a_d, (const unsigned int*)X8b, MEAN, N2);
    k_pool<<<2 * GG, 128, 0, stream>>>(MEAN, L3, b3, batch_l, batch_r, n, (float*)d_out);
}

// Round 14
// 418.824 us; speedup vs baseline: 1.0740x; 1.0740x over previous
//
#include <hip/hip_runtime.h>

#define GG 256

typedef __bf16 bf16x8 __attribute__((ext_vector_type(8)));
typedef __bf16 bf16x4 __attribute__((ext_vector_type(4)));
typedef float floatx4 __attribute__((ext_vector_type(4)));
typedef float f32x2 __attribute__((ext_vector_type(2)));

__device__ __forceinline__ float lrelu(float x) { return x > 0.f ? x : 0.2f * x; }

// column permutation within each 64-col group: compute-order -> consecutive true cols
__device__ __forceinline__ int permM(int m) {
    int g = m >> 6, q = m & 63;
    return (g << 6) | ((q & 3) << 4) | (q >> 2);
}

// ---- fused weight prep (B rows stored permuted; attn mini-tile unpermuted) ----
__device__ __forceinline__ void wt1(const float* __restrict__ B, __bf16* __restrict__ Bt,
                                    int K, int M, int idx) {
    int k = idx / M, m = idx - k * M;
    Bt[(size_t)permM(m) * K + k] = (__bf16)B[idx];
}
__device__ __forceinline__ void wattn1(const float* __restrict__ W,
                                       const float* __restrict__ as_,
                                       const float* __restrict__ ad_,
                                       __bf16* __restrict__ dst, int K, int C, int idx) {
    int j = idx / K, k = idx - j * K;
    float v = 0.f;
    if (j < 8) {
        int h = j & 3;
        const float* att = (j < 4) ? as_ : ad_;
        int M = 4 * C;
        for (int c = 0; c < C; c++) v += W[(size_t)k * M + h * C + c] * att[h * C + c];
    }
    dst[(size_t)j * K + k] = (__bf16)v;
}

__global__ void k_wprep(const float* W1, const float* lw1, const float* as1, const float* ad1,
                        const float* W2, const float* lw2, const float* as2, const float* ad2,
                        const float* W3, const float* lw3, const float* as3, const float* ad3,
                        __bf16* B1t, __bf16* B2t, __bf16* B3t) {
    int idx = blockIdx.x * blockDim.x + threadIdx.x;
    if (idx < 32768) { wt1(W1, B1t, 128, 256, idx); return; }
    idx -= 32768;
    if (idx < 32768) { wt1(lw1, B1t + 256 * 128, 128, 256, idx); return; }
    idx -= 32768;
    if (idx < 2048) { wattn1(W1, as1, ad1, B1t + 512 * 128, 128, 64, idx); return; }
    idx -= 2048;
    if (idx < 65536) { wt1(W2, B2t, 256, 256, idx); return; }
    idx -= 65536;
    if (idx < 65536) { wt1(lw2, B2t + 256 * 256, 256, 256, idx); return; }
    idx -= 65536;
    if (idx < 4096) { wattn1(W2, as2, ad2, B2t + 512 * 256, 256, 64, idx); return; }
    idx -= 4096;
    if (idx < 131072) { wt1(W3, B3t, 256, 512, idx); return; }
    idx -= 131072;
    if (idx < 32768) { wt1(lw3, B3t + 512 * 256, 256, 128, idx); return; }
    idx -= 32768;
    if (idx < 4096) { wattn1(W3, as3, ad3, B3t + 640 * 256, 256, 128, idx); }
}

// All-in-one GEMM (64-row blocks, register-pipelined B staging, packed epilogue).
template <int K, bool EMB, bool LINBF>
__global__ __launch_bounds__(256) void k_gemm_all(const __bf16* __restrict__ A,
                                                  const int* __restrict__ xl,
                                                  const int* __restrict__ xr,
                                                  const float* __restrict__ emb,
                                                  const __bf16* __restrict__ Bt,
                                                  int n, int n1, int Mx, int Ml,
                                                  unsigned char* __restrict__ x8, int ldx,
                                                  float* __restrict__ linf,
                                                  __bf16* __restrict__ linb, int ldl,
                                                  const float* __restrict__ bias1,
                                                  const float* __restrict__ bias2,
                                                  float* __restrict__ a_s,
                                                  float* __restrict__ a_d) {
    constexpr int KS = K / 32;
    constexpr int LDK = K + 8;
    constexpr int LPR = K / 8;
    constexpr int NCH = 64 * LPR / 256;
    __shared__ __bf16 S[64 * LDK];
    int tid = threadIdx.x;
    int wave = tid >> 6, lane = tid & 63;
    int row0 = blockIdx.x * 64;
#pragma unroll
    for (int c = 0; c < NCH; c++) {
        int i = tid + c * 256;
        int r = i / LPR, ko = (i - r * LPR) * 8;
        int gr = row0 + r;
        bf16x8 v = {};
        if (gr < n) {
            if (EMB) {
                int xi = (gr < n1) ? xl[gr] : xr[gr - n1];
                const float4* src = (const float4*)(emb + ((size_t)xi << 7) + ko);
                float4 q0 = src[0], q1 = src[1];
                v = bf16x8{(__bf16)q0.x, (__bf16)q0.y, (__bf16)q0.z, (__bf16)q0.w,
                           (__bf16)q1.x, (__bf16)q1.y, (__bf16)q1.z, (__bf16)q1.w};
            } else {
                v = *(const bf16x8*)(A + (size_t)gr * K + ko);
            }
        }
        *(bf16x8*)&S[r * LDK + ko] = v;
    }
    __syncthreads();
    int kOff = (lane >> 4) * 8;
    int colBase = lane & 15;
    bf16x8 af[KS];
#pragma unroll
    for (int ks = 0; ks < KS; ks++)
        af[ks] = *(const bf16x8*)&S[(wave * 16 + colBase) * LDK + ks * 32 + kOff];
    int Mtot = Mx + Ml;
    int gr0 = row0 + wave * 16 + ((lane >> 4) << 2);
    int half = (Mtot / 128) * 64;
    int c0beg = blockIdx.y * half;
    int T = half / 64;
    bf16x8 regs[NCH];
#pragma unroll
    for (int c = 0; c < NCH; c++) {
        int i = tid + c * 256;
        int r = i / LPR, ko = (i - r * LPR) * 8;
        regs[c] = *(const bf16x8*)(Bt + (size_t)(c0beg + r) * K + ko);
    }
    for (int t = 0; t < T; t++) {
        __syncthreads();
#pragma unroll
        for (int c = 0; c < NCH; c++) {
            int i = tid + c * 256;
            int r = i / LPR, ko = (i - r * LPR) * 8;
            *(bf16x8*)&S[r * LDK + ko] = regs[c];
        }
        if (t + 1 < T) {
            int c0n = c0beg + (t + 1) * 64;
#pragma unroll
            for (int c = 0; c < NCH; c++) {
                int i = tid + c * 256;
                int r = i / LPR, ko = (i - r * LPR) * 8;
                regs[c] = *(const bf16x8*)(Bt + (size_t)(c0n + r) * K + ko);
            }
        }
        __syncthreads();
        floatx4 acc[4] = {};
#pragma unroll
        for (int ct = 0; ct < 4; ct++) {
#pragma unroll
            for (int ks = 0; ks < KS; ks++) {
                bf16x8 bf = *(const bf16x8*)&S[(ct * 16 + colBase) * LDK + ks * 32 + kOff];
                acc[ct] = __builtin_amdgcn_mfma_f32_16x16x32_bf16(af[ks], bf, acc[ct], 0, 0, 0);
            }
        }
        int c0 = c0beg + t * 64;
        if (c0 < Mx) {  // packed fp8 dword store per row
#pragma unroll
            for (int r = 0; r < 4; r++) {
                int gr = gr0 + r;
                if (gr >= n) continue;
                int p = __builtin_amdgcn_cvt_pk_fp8_f32(acc[0][r], acc[1][r], 0, false);
                p = __builtin_amdgcn_cvt_pk_fp8_f32(acc[2][r], acc[3][r], p, true);
                *(unsigned int*)(x8 + (size_t)gr * ldx + c0 + colBase * 4) = (unsigned int)p;
            }
        } else {
            int c2 = c0 + colBase * 4 - Mx;
#pragma unroll
            for (int r = 0; r < 4; r++) {
                int gr = gr0 + r;
                if (gr >= n) continue;
                float v0 = acc[0][r] + bias1[c2 + 0];
                float v1 = acc[1][r] + bias1[c2 + 1];
                float v2 = acc[2][r] + bias1[c2 + 2];
                float v3 = acc[3][r] + bias1[c2 + 3];
                if (bias2) {
                    v0 += bias2[c2 + 0]; v1 += bias2[c2 + 1];
                    v2 += bias2[c2 + 2]; v3 += bias2[c2 + 3];
                }
                if (LINBF) {
                    bf16x4 o = {(__bf16)v0, (__bf16)v1, (__bf16)v2, (__bf16)v3};
                    *(bf16x4*)(linb + (size_t)gr * ldl + c2) = o;
                } else {
                    float4 o = {v0, v1, v2, v3};
                    *(float4*)(linf + (size_t)gr * ldl + c2) = o;
                }
            }
        }
    }
    if (blockIdx.y == 1) {  // attn mini-tile (unpermuted rows)
        floatx4 acc = {};
        const __bf16* bp = Bt + (size_t)(Mtot + colBase) * K + kOff;
#pragma unroll
        for (int ks = 0; ks < KS; ks++) {
            bf16x8 bf = *(const bf16x8*)(bp + ks * 32);
            acc = __builtin_amdgcn_mfma_f32_16x16x32_bf16(af[ks], bf, acc, 0, 0, 0);
        }
        if (colBase < 8) {
            float* dst = (colBase < 4) ? a_s : a_d;
            int h = colBase & 3;
#pragma unroll
            for (int r = 0; r < 4; r++) {
                int gr = gr0 + r;
                if (gr < n) dst[gr * 4 + h] = acc[r];
            }
        }
    }
}

// ---- combined-CSR build (side-1 ids offset by n) ----
__global__ void k_hist2(const int* __restrict__ el, const int* __restrict__ er,
                        int E, int n, int* __restrict__ deg) {
    int e = blockIdx.x * blockDim.x + threadIdx.x;
    if (e >= 2 * E) return;
    int d = (e < E) ? el[E + e] : er[E + (e - E)] + n;
    atomicAdd(&deg[d], 1);
}

// ---- 3-pass parallel exclusive scan over rp[0..n) ----
__global__ __launch_bounds__(1024) void k_scan1(int* __restrict__ rp, int n,
                                                int* __restrict__ part) {
    __shared__ int wsum[16];
    int i = blockIdx.x * 1024 + threadIdx.x;
    int lane = threadIdx.x & 63, wid = threadIdx.x >> 6;
    int v = (i < n) ? rp[i] : 0;
    int inc = v;
#pragma unroll
    for (int off = 1; off < 64; off <<= 1) {
        int t = __shfl_up(inc, off, 64);
        if (lane >= off) inc += t;
    }
    if (lane == 63) wsum[wid] = inc;
    __syncthreads();
    if (wid == 0) {
        int wv = (lane < 16) ? wsum[lane] : 0;
        int winc = wv;
#pragma unroll
        for (int off = 1; off < 16; off <<= 1) {
            int t = __shfl_up(winc, off, 64);
            if (lane >= off) winc += t;
        }
        if (lane < 16) wsum[lane] = winc - wv;  // exclusive wave offsets
        if (lane == 15) part[blockIdx.x] = winc;  // block total
    }
    __syncthreads();
    if (i < n) rp[i] = wsum[wid] + (inc - v);  // block-local exclusive
}

__global__ void k_scan2(int* __restrict__ part, int nb) {
    int lane = threadIdx.x;
    int v = (lane < nb) ? part[lane] : 0;
    int inc = v;
#pragma unroll
    for (int off = 1; off < 64; off <<= 1) {
        int t = __shfl_up(inc, off, 64);
        if (lane >= off) inc += t;
    }
    if (lane < nb) part[lane] = inc - v;  // exclusive
}

__global__ __launch_bounds__(1024) void k_scan3(int* __restrict__ rp, int n,
                                                const int* __restrict__ part) {
    int i = blockIdx.x * 1024 + threadIdx.x;
    if (i < n) rp[i] += part[blockIdx.x];
}

__global__ void k_fill2(const int* __restrict__ el, const int* __restrict__ er,
                        int E, int n, int* __restrict__ rp, int* __restrict__ csr) {
    int e = blockIdx.x * blockDim.x + threadIdx.x;
    if (e >= 2 * E) return;
    int d, s;
    if (e < E) { s = el[e]; d = el[E + e]; }
    else       { s = er[e - E] + n; d = er[E + (e - E)] + n; }
    int pos = atomicAdd(&rp[d], 1);
    csr[pos] = s;
}

template <bool HI>
__device__ __forceinline__ f32x2 cvt2(unsigned int u) {
    return __builtin_amdgcn_cvt_pk_f32_fp8(u, HI);
}

// side-split XCD swizzle: blocks with bid%8 in {0..3} take side-L node blocks,
// {4..7} take side-R -> each XCD's gather footprint is one side's table only.
__device__ __forceinline__ int swz_block(int bid, int nbx) {
    if (nbx & 7) return bid;           // safety: needs nbx % 8 == 0
    int halfb = nbx >> 1;
    int grp = bid >> 3, r = bid & 7;
    int j = grp * 4 + (r & 3);
    return (r < 4) ? j : halfb + j;
}

// Layers 1/2 aggregation on fp8 rows (256 B): ONE node per wave, FOUR
// quarter-wave edge streams (16 lanes x 16 B each) -> 4 edges/iteration,
// loop length ceil(d/4). Rotating depth-3 prefetch (unroll-3 renames the
// rotation away); clamped in-loop prefetch. f32x2 packed accumulation
// (v_pk_fma_f32). Cross-quarter merge via shfl_xor(16)+shfl_xor(32).
__global__ __launch_bounds__(256) void k_agg12(const int* __restrict__ rp,
                                               const int* __restrict__ csr,
                                               const float* __restrict__ a_s,
                                               const float* __restrict__ a_d,
                                               const unsigned char* __restrict__ x8,
                                               const __bf16* __restrict__ lin,
                                               __bf16* __restrict__ out_bf, int n) {
    int nb = swz_block(blockIdx.x, gridDim.x);
    int lane = threadIdx.x & 63;
    int q = lane >> 4, sl = lane & 15;
    int node = nb * 4 + (threadIdx.x >> 6);
    if (node >= n) return;
    int c0 = sl * 16;   // byte/value column in 256-wide row
    int h = sl >> 2;
    int start = node ? rp[node - 1] : 0;
    int end = rp[node];
    float ad = a_d[node * 4 + h];
    float z = 0.f;
    f32x2 acc[8] = {};  // value j lives at acc[j>>1][j&1]
    if (q == 0) {  // self-loop term once
        z = __expf(lrelu(a_s[node * 4 + h] + ad));
        uint4 u = *(const uint4*)(x8 + (size_t)node * 256 + c0);
        f32x2 zz = {z, z};
        acc[0] = zz * cvt2<false>(u.x); acc[1] = zz * cvt2<true>(u.x);
        acc[2] = zz * cvt2<false>(u.y); acc[3] = zz * cvt2<true>(u.y);
        acc[4] = zz * cvt2<false>(u.z); acc[5] = zz * cvt2<true>(u.z);
        acc[6] = zz * cvt2<false>(u.w); acc[7] = zz * cvt2<true>(u.w);
    }
    uint4 u0 = {}, u1 = {}, u2 = {};
    float A0 = 0.f, A1 = 0.f, A2 = 0.f;
    int e0 = start + q;
    if (e0 < end) {
        int s = csr[e0];
        u0 = *(const uint4*)(x8 + (size_t)s * 256 + c0);
        A0 = a_s[s * 4 + h];
    }
    if (e0 + 4 < end) {
        int s = csr[e0 + 4];
        u1 = *(const uint4*)(x8 + (size_t)s * 256 + c0);
        A1 = a_s[s * 4 + h];
    }
    if (e0 + 8 < end) {
        int s = csr[e0 + 8];
        u2 = *(const uint4*)(x8 + (size_t)s * 256 + c0);
        A2 = a_s[s * 4 + h];
    }
#pragma unroll 3
    for (int e = e0; e < end; e += 4) {
        uint4 uc = u0;
        float ac = A0;
        u0 = u1; A0 = A1;
        u1 = u2; A1 = A2;
        int pn = e + 12;
        pn = pn < end ? pn : end - 1;  // loop entered => end >= 1
        int s = csr[pn];
        u2 = *(const uint4*)(x8 + (size_t)s * 256 + c0);
        A2 = a_s[s * 4 + h];
        float w = __expf(lrelu(ac + ad));
        z += w;
        f32x2 wv = {w, w};
        acc[0] += wv * cvt2<false>(uc.x); acc[1] += wv * cvt2<true>(uc.x);
        acc[2] += wv * cvt2<false>(uc.y); acc[3] += wv * cvt2<true>(uc.y);
        acc[4] += wv * cvt2<false>(uc.z); acc[5] += wv * cvt2<true>(uc.z);
        acc[6] += wv * cvt2<false>(uc.w); acc[7] += wv * cvt2<true>(uc.w);
    }
    z += __shfl_xor(z, 16, 64);
    z += __shfl_xor(z, 32, 64);
#pragma unroll
    for (int k = 0; k < 8; k++) {
#pragma unroll
        for (int e2 = 0; e2 < 2; e2++) {
            float v = acc[k][e2];
            v += __shfl_xor(v, 16, 64);
            v += __shfl_xor(v, 32, 64);
            acc[k][e2] = v;
        }
    }
    if (q == 0) {
        float inv = 1.f / (z + 1e-16f);
        const __bf16* lp = lin + (size_t)node * 256 + c0;
        bf16x8 l0 = *(const bf16x8*)lp;
        bf16x8 l1 = *(const bf16x8*)(lp + 8);
        bf16x8 r0, r1;
#pragma unroll
        for (int j = 0; j < 8; j++) {
            r0[j] = (__bf16)fmaxf(acc[j >> 1][j & 1] * inv + (float)l0[j], 0.f);
            r1[j] = (__bf16)fmaxf(acc[4 + (j >> 1)][j & 1] * inv + (float)l1[j], 0.f);
        }
        __bf16* op = out_bf + (size_t)node * 256 + c0;
        *(bf16x8*)op = r0;
        *(bf16x8*)(op + 8) = r1;
    }
}

// Layer-3 aggregation (HC=512): ONE node per wave, even/odd edge halves
// (32 lanes x 16 B each), rotating depth-3 prefetch (unroll-3 renames the
// rotation), clamped in-loop prefetch, f32x2 packed accumulation.
// Head-mean via shfl; lanes 0-7 store mean[n,128].
__global__ __launch_bounds__(256) void k_agg3(const int* __restrict__ rp,
                                              const int* __restrict__ csr,
                                              const float* __restrict__ a_s,
                                              const float* __restrict__ a_d,
                                              const unsigned int* __restrict__ x8,
                                              float* __restrict__ mean, int n) {
    int nb = swz_block(blockIdx.x, gridDim.x);
    int lane = threadIdx.x & 63;
    int half = lane >> 5, sl = lane & 31;
    int node = nb * 4 + (threadIdx.x >> 6);
    if (node >= n) return;
    int h = sl >> 3;
    int start = node ? rp[node - 1] : 0;
    int end = rp[node];
    float ad = a_d[node * 4 + h];
    float z = 0.f;
    f32x2 acc[8] = {};  // value j lives at acc[j>>1][j&1]
    if (half == 0) {  // self-loop term once
        z = __expf(lrelu(a_s[node * 4 + h] + ad));
        uint4 u = *(const uint4*)(x8 + (size_t)node * 128 + sl * 4);
        f32x2 zz = {z, z};
        acc[0] = zz * cvt2<false>(u.x); acc[1] = zz * cvt2<true>(u.x);
        acc[2] = zz * cvt2<false>(u.y); acc[3] = zz * cvt2<true>(u.y);
        acc[4] = zz * cvt2<false>(u.z); acc[5] = zz * cvt2<true>(u.z);
        acc[6] = zz * cvt2<false>(u.w); acc[7] = zz * cvt2<true>(u.w);
    }
    uint4 u0 = {}, u1 = {}, u2 = {};
    float A0 = 0.f, A1 = 0.f, A2 = 0.f;
    int e0 = start + half;
    if (e0 < end) {
        int s = csr[e0];
        u0 = *(const uint4*)(x8 + (size_t)s * 128 + sl * 4);
        A0 = a_s[s * 4 + h];
    }
    if (e0 + 2 < end) {
        int s = csr[e0 + 2];
        u1 = *(const uint4*)(x8 + (size_t)s * 128 + sl * 4);
        A1 = a_s[s * 4 + h];
    }
    if (e0 + 4 < end) {
        int s = csr[e0 + 4];
        u2 = *(const uint4*)(x8 + (size_t)s * 128 + sl * 4);
        A2 = a_s[s * 4 + h];
    }
#pragma unroll 3
    for (int e = e0; e < end; e += 2) {
        uint4 uc = u0;
        float ac = A0;
        u0 = u1; A0 = A1;
        u1 = u2; A1 = A2;
        int pn = e + 6;
        pn = pn < end ? pn : end - 1;  // loop entered => end >= 1
        int s = csr[pn];
        u2 = *(const uint4*)(x8 + (size_t)s * 128 + sl * 4);
        A2 = a_s[s * 4 + h];
        float w = __expf(lrelu(ac + ad));
        z += w;
        f32x2 wv = {w, w};
        acc[0] += wv * cvt2<false>(uc.x); acc[1] += wv * cvt2<true>(uc.x);
        acc[2] += wv * cvt2<false>(uc.y); acc[3] += wv * cvt2<true>(uc.y);
        acc[4] += wv * cvt2<false>(uc.z); acc[5] += wv * cvt2<true>(uc.z);
        acc[6] += wv * cvt2<false>(uc.w); acc[7] += wv * cvt2<true>(uc.w);
    }
    z += __shfl_xor(z, 32, 64);   // merge edge halves -> full denominator
    float sc = 0.25f / (z + 1e-16f);
#pragma unroll
    for (int k = 0; k < 8; k++) {
#pragma unroll
        for (int e2 = 0; e2 < 2; e2++) {
            float v = acc[k][e2];
            v += __shfl_xor(v, 32, 64);   // merge edge halves
            v *= sc;                      // per-head scale
            v += __shfl_xor(v, 8, 64);    // merge head pair
            v += __shfl_xor(v, 16, 64);   // merge remaining heads
            acc[k][e2] = v;
        }
    }
    if (lane < 8) {  // lanes 0-7 hold mean cols 16*sl .. 16*sl+15
        float4* op = (float4*)(mean + (size_t)node * 128 + lane * 16);
#pragma unroll
        for (int k = 0; k < 4; k++) {
            float4 o = {acc[2 * k][0], acc[2 * k][1], acc[2 * k + 1][0], acc[2 * k + 1][1]};
            op[k] = o;
        }
    }
}

// per-graph mean pool (2G blocks), inline binary search on sorted batch
__global__ __launch_bounds__(128) void k_pool(const float* __restrict__ mean,
                                              const float* __restrict__ lin3,
                                              const float* __restrict__ b3,
                                              const int* __restrict__ bl,
                                              const int* __restrict__ br,
                                              int n, float* __restrict__ out) {
    int g = blockIdx.x, c = threadIdx.x;
    const int* b = (g < GG) ? bl : br;
    int tg = (g < GG) ? g : g - GG;
    int off = (g < GG) ? 0 : n;
    int s, e;
    { int lo = 0, hi = n; while (lo < hi) { int m = (lo + hi) >> 1; if (b[m] < tg) lo = m + 1; else hi = m; } s = lo; }
    { int lo = 0, hi = n; while (lo < hi) { int m = (lo + hi) >> 1; if (b[m] < tg + 1) lo = m + 1; else hi = m; } e = lo; }
    s += off; e += off;
    float acc = 0.f;
    for (int i = s; i < e; i++)
        acc += mean[(size_t)i * 128 + c] + lin3[(size_t)i * 128 + c];
    int cnt = e - s;
    out[(size_t)g * 128 + c] = cnt > 0 ? acc / (float)cnt + b3[c] : 0.f;
}

static inline int cdiv(int a, int b) { return (a + b - 1) / b; }

extern "C" void kernel_launch(void* const* d_in, const int* in_sizes, int n_in,
                              void* d_out, int out_size, void* d_ws, size_t ws_size,
                              hipStream_t stream) {
    const int* x_l = (const int*)d_in[0];
    const int* edge_l = (const int*)d_in[1];
    const int* batch_l = (const int*)d_in[2];
    const int* x_r = (const int*)d_in[3];
    const int* edge_r = (const int*)d_in[4];
    const int* batch_r = (const int*)d_in[5];
    const float* emb = (const float*)d_in[6];
    const float* W1 = (const float*)d_in[7];
    const float* as1 = (const float*)d_in[8];
    const float* ad1 = (const float*)d_in[9];
    const float* b1 = (const float*)d_in[10];
    const float* lw1 = (const float*)d_in[11];
    const float* lb1 = (const float*)d_in[12];
    const float* W2 = (const float*)d_in[13];
    const float* as2 = (const float*)d_in[14];
    const float* ad2 = (const float*)d_in[15];
    const float* b2 = (const float*)d_in[16];
    const float* lw2 = (const float*)d_in[17];
    const float* lb2 = (const float*)d_in[18];
    const float* W3 = (const float*)d_in[19];
    const float* as3 = (const float*)d_in[20];
    const float* ad3 = (const float*)d_in[21];
    const float* b3 = (const float*)d_in[22];
    const float* lw3 = (const float*)d_in[23];
    const float* lb3 = (const float*)d_in[24];

    const int n = in_sizes[0];       // 20000
    const int E = in_sizes[1] / 2;   // 320000
    const int N2 = 2 * n;
    const int NB = cdiv(N2, 1024);   // scan blocks (40 <= 64)

    float* MEAN = (float*)d_ws;                // [N2,128]
    float* L3 = MEAN + (size_t)N2 * 128;       // [N2,128] fp32 layer-3 skip
    float* a_s = L3 + (size_t)N2 * 128;        // [N2,4]
    float* a_d = a_s + (size_t)N2 * 4;
    int* rp = (int*)(a_d + (size_t)N2 * 4);    // [N2]
    int* csr = rp + N2;                        // [2E]
    int* part = csr + 2 * E;                   // [64] scan partials
    __bf16* LINb = (__bf16*)(part + 64);       // [N2,256] bf16 skip (layers 1/2)
    unsigned char* X8a = (unsigned char*)(LINb + (size_t)N2 * 256);  // [N2,256] fp8
    unsigned char* X8b = X8a + (size_t)N2 * 256;                     // [N2,512] fp8
    __bf16* Abf = (__bf16*)(X8b + (size_t)N2 * 512);                 // [N2,256] GEMM A
    __bf16* B1t = Abf + (size_t)N2 * 256;  // 528 x 128
    __bf16* B2t = B1t + 528 * 128;         // 528 x 256
    __bf16* B3t = B2t + 528 * 256;         // 656 x 256

    const int TB = 256;
    dim3 blk(TB);

    // fused weight prep (1 dispatch)
    k_wprep<<<cdiv(370688, TB), blk, 0, stream>>>(W1, lw1, as1, ad1, W2, lw2, as2, ad2,
                                                  W3, lw3, as3, ad3, B1t, B2t, B3t);

    // combined CSR (once for all 3 layers, both sides), parallel scan
    hipMemsetAsync(rp, 0, sizeof(int) * (size_t)N2, stream);
    k_hist2<<<cdiv(2 * E, TB), blk, 0, stream>>>(edge_l, edge_r, E, n, rp);
    k_scan1<<<NB, 1024, 0, stream>>>(rp, N2, part);
    k_scan2<<<1, 64, 0, stream>>>(part, NB);
    k_scan3<<<NB, 1024, 0, stream>>>(rp, N2, part);
    k_fill2<<<cdiv(2 * E, TB), blk, 0, stream>>>(edge_l, edge_r, E, n, rp, csr);

    // ---- layer 1 (K=128, embed fused, Mx=256 -> fp8, Ml=256 -> bf16 lin) ----
    k_gemm_all<128, true, true><<<dim3(cdiv(N2, 64), 2), blk, 0, stream>>>(
        nullptr, x_l, x_r, emb, B1t, N2, n, 256, 256, X8a, 256, nullptr, LINb, 256, lb1, b1, a_s, a_d);
    k_agg12<<<cdiv(N2, 4), blk, 0, stream>>>(rp, csr, a_s, a_d, X8a, LINb, Abf, N2);

    // ---- layer 2 (K=256, Mx=256 -> fp8, Ml=256 -> bf16 lin) ----
    k_gemm_all<256, false, true><<<dim3(cdiv(N2, 64), 2), blk, 0, stream>>>(
        Abf, nullptr, nullptr, nullptr, B2t, N2, n, 256, 256, X8a, 256, nullptr, LINb, 256, lb2, b2, a_s, a_d);
    k_agg12<<<cdiv(N2, 4), blk, 0, stream>>>(rp, csr, a_s, a_d, X8a, LINb, Abf, N2);

    // ---- layer 3 (K=256, Mx=512 -> fp8, Ml=128 -> fp32 L3) ----
    k_gemm_all<256, false, false><<<dim3(cdiv(N2, 64), 2), blk, 0, stream>>>(
        Abf, nullptr, nullptr, nullptr, B3t, N2, n, 512, 128, X8b, 512, L3, nullptr, 128, lb3, nullptr, a_s, a_d);
    k_agg3<<<cdiv(N2, 4), blk, 0, stream>>>(rp, csr, a_s, a_d, (const unsigned int*)X8b, MEAN, N2);
    k_pool<<<2 * GG, 128, 0, stream>>>(MEAN, L3, b3, batch_l, batch_r, n, (float*)d_out);
}